// Round 7
// baseline (203.708 us; speedup 1.0000x reference)
//
#include <hip/hip_runtime.h>
#include <math.h>

#define NBINS 1000
#define NDIM 64
#define DIMS_PER_BLOCK 8
#define DIM_GROUPS (NDIM / DIMS_PER_BLOCK)      // 8
#define BLOCK_THREADS 1024
#define ROWS_PER_ITER 1024                       // 2 rows/thread, 2 threads/row
#define ROW_HALF 512                             // rB = rA + ROW_HALF (same chunk!)
#define ROW_BLOCKS 64                            // 512 blocks = 2/CU, all resident
                                                 // (single generation). 64%8==0 ->
                                                 // all 8 dim-groups of a chunk on one
                                                 // XCD; concurrent window = 8 chunks
                                                 // x 1024 rows x 256B = 2MB < 4MB L2
                                                 // -> partial-line merge OK.
                                                 // RULES (measured): never shrink
                                                 // per-block row footprint below 32B
                                                 // (R5: 3x traffic); never interleave
                                                 // rows from different chunks (R3).

// zero the log_det region (atomic fallback path only)
__global__ __launch_bounds__(1024) void mg_zero(float* __restrict__ p, int n) {
    int i = blockIdx.x * blockDim.x + threadIdx.x;
    if (i < n) p[i] = 0.0f;
}

// final reduce: log_det[row] = sum over 8 dim-group partials in ws
__global__ __launch_bounds__(256) void mg_reduce(const float* __restrict__ ws,
                                                 float* __restrict__ out, int B) {
    int row = blockIdx.x * blockDim.x + threadIdx.x;
    if (row >= B) return;
    float s = 0.0f;
#pragma unroll
    for (int g = 0; g < DIM_GROUPS; ++g) s += ws[(size_t)g * B + row];
    out[row] = s;
}

// per-dim math in e-space: tables store c' = 2c-1, so e = c'_l + slope2*(x-x_l)
// directly (no fmaf(2,u,-1)); slope2 = 2*slope; p_hat = slope2/2 folded into the
// additive constant of the log-det term. e-clamp +-0.99999 subsumes the ref's
// u-clip to (1e-6, 1-1e-6) exactly. Fix-up walk compares STORED x knots -> bin
// selection stays exact. MACRO so knots[] stays a direct LDS access.
#define DIM_MATH(xd_, base_, i_, a_, b_, sc_, php_, ss_, zout_)                   \
    {                                                                             \
        float xd = (xd_);                                                         \
        int i = (i_);                                                             \
        float2 a = (a_), b = (b_);                                                \
        if (__builtin_expect((xd > b.x && i < NBINS - 2) ||                       \
                             (xd <= a.x && i > 0), 0)) {                          \
            while (xd > b.x && i < NBINS - 2) {                                   \
                ++i; a = b; b = knots[(base_) + i + 1];                           \
            }                                                                     \
            while (xd <= a.x && i > 0) {                                          \
                --i; b = a; a = knots[(base_) + i];                               \
            }                                                                     \
        }                                                                         \
        float slope2 = (b.y - a.y) * (sc_);     /* = 2*p_hat (per-dim inv-step) */\
        float e = fmaf(slope2, xd - a.x, a.y);                                    \
        float ph2 = fmaxf(slope2, 2e-12f);                                        \
        float e1 = fminf(fmaxf(e, -0.99999f), 0.99999f);                          \
        float wv = -0.6931471805599453f *                                         \
                   __builtin_amdgcn_logf(fmaf(-e1, e1, 1.0f));                    \
        float t = wv - 2.5f;                                                      \
        float p = 2.81022636e-08f;                                                \
        p = fmaf(p, t, 3.43273939e-07f);                                          \
        p = fmaf(p, t, -3.5233877e-06f);                                          \
        p = fmaf(p, t, -4.39150654e-06f);                                         \
        p = fmaf(p, t, 0.00021858087f);                                           \
        p = fmaf(p, t, -0.00125372503f);                                          \
        p = fmaf(p, t, -0.00417768164f);                                          \
        p = fmaf(p, t, 0.246640727f);                                             \
        p = fmaf(p, t, 1.50140941f);                                              \
        if (wv >= 5.0f) {                                                         \
            float tq = sqrtf(wv) - 3.0f;                                          \
            float pt = -0.000200214257f;                                          \
            pt = fmaf(pt, tq, 0.000100950558f);                                   \
            pt = fmaf(pt, tq, 0.00134934322f);                                    \
            pt = fmaf(pt, tq, -0.00367342844f);                                   \
            pt = fmaf(pt, tq, 0.00573950773f);                                    \
            pt = fmaf(pt, tq, -0.0076224613f);                                    \
            pt = fmaf(pt, tq, 0.00943887047f);                                    \
            pt = fmaf(pt, tq, 1.00167406f);                                       \
            pt = fmaf(pt, tq, 2.83297682f);                                       \
            p = pt;                                                               \
        }                                                                         \
        float z = 1.4142135623730951f * p * e1; /* |z|<=4.418, ref clamp dead */  \
        (zout_) = z;                                                              \
        (ss_) = fmaf(z, z, (ss_));                                                \
        (php_) *= ph2;                                                            \
    }

// lane0<->lane1 pair swap as pure VALU (DPP quad_perm [1,0,3,2] = 0xB1).
// No lgkm event -> the reduce never drains outstanding LDS gathers (R6 win).
__device__ __forceinline__ float pair_swap_dpp(float v) {
    return __int_as_float(__builtin_amdgcn_update_dpp(
        __float_as_int(v), __float_as_int(v), 0xB1, 0xF, 0xF, true));
}

// Block owns 8 dims; knots (x_i, 2c_i-1) staged in LDS (64 KB).
// Each thread: 4 dims of TWO rows (rA, rB=rA+512, same 1024-row chunk).
// Body: issue next x loads -> bins+gathers for A AND B (16 reads in flight)
// -> mathA (short lgkm wait) -> mathB (free: mathA was its slack) -> stores +
// DPP reduce. 4 bodies/thread: loop overhead halved vs R6, 8 indep chains.
template <bool USE_WS>
__global__ __launch_bounds__(BLOCK_THREADS, 8)
void mg_main(const float* __restrict__ x,
             const float* __restrict__ xvals,
             const float* __restrict__ cdf,
             float* __restrict__ out, float* __restrict__ ws, int B) {
    __shared__ float2 knots[DIMS_PER_BLOCK * NBINS];   // 64000 B

    const int dimbase = blockIdx.y * DIMS_PER_BLOCK;

    {   // vectorized stage: 2000 float4s from each table; c -> 2c-1 (e-space)
        const float4* xv4 = (const float4*)(xvals + (size_t)dimbase * NBINS);
        const float4* cd4 = (const float4*)(cdf + (size_t)dimbase * NBINS);
        for (int k = threadIdx.x; k < DIMS_PER_BLOCK * NBINS / 4; k += BLOCK_THREADS) {
            float4 a = xv4[k], c = cd4[k];
            knots[k * 4 + 0] = make_float2(a.x, fmaf(2.0f, c.x, -1.0f));
            knots[k * 4 + 1] = make_float2(a.y, fmaf(2.0f, c.y, -1.0f));
            knots[k * 4 + 2] = make_float2(a.z, fmaf(2.0f, c.z, -1.0f));
            knots[k * 4 + 3] = make_float2(a.w, fmaf(2.0f, c.w, -1.0f));
        }
    }
    __syncthreads();

    const int dl = (threadIdx.x & 1) * 4;                // local dims dl..dl+3
    const int qidx = blockIdx.y * 2 + (threadIdx.x & 1); // float4 index within row

    float scale[4], bias[4];
#pragma unroll
    for (int j = 0; j < 4; ++j) {
        float l = knots[(dl + j) * NBINS].x;
        float h = knots[(dl + j) * NBINS + NBINS - 1].x;
        float s = (float)(NBINS - 1) / (h - l);          // == 1/step_d
        scale[j] = s;
        bias[j] = -l * s;
    }

    const int rstride = gridDim.x * ROWS_PER_ITER;       // 65536
    int rA = blockIdx.x * ROWS_PER_ITER + (threadIdx.x >> 1);

    float4 xqA = make_float4(0.f, 0.f, 0.f, 0.f);
    float4 xqB = make_float4(0.f, 0.f, 0.f, 0.f);
    if (rA < B) xqA = ((const float4*)x)[(size_t)rA * (NDIM / 4) + qidx];
    if (rA + ROW_HALF < B)
        xqB = ((const float4*)x)[(size_t)(rA + ROW_HALF) * (NDIM / 4) + qidx];

    for (; rA < B; rA += rstride) {
        const int rB = rA + ROW_HALF;
        // issue next-body x loads (consumed next body: full-body slack >> HBM lat)
        const int pA = rA + rstride, pB = rB + rstride;
        float4 xnA = make_float4(0.f, 0.f, 0.f, 0.f);
        float4 xnB = make_float4(0.f, 0.f, 0.f, 0.f);
        if (pA < B) xnA = ((const float4*)x)[(size_t)pA * (NDIM / 4) + qidx];
        if (pB < B) xnB = ((const float4*)x)[(size_t)pB * (NDIM / 4) + qidx];

        // bins + gathers for BOTH rows: 16 ds_reads in flight together
        int iA[4], iB[4];
        float2 klA[4], krA[4], klB[4], krB[4];
#pragma unroll
        for (int j = 0; j < 4; ++j) {
            int i = (int)fmaf(((const float*)&xqA)[j], scale[j], bias[j]);
            iA[j] = min(max(i, 0), NBINS - 2);
            i = (int)fmaf(((const float*)&xqB)[j], scale[j], bias[j]);
            iB[j] = min(max(i, 0), NBINS - 2);
        }
#pragma unroll
        for (int j = 0; j < 4; ++j) {
            klA[j] = knots[(dl + j) * NBINS + iA[j]];
            krA[j] = knots[(dl + j) * NBINS + iA[j] + 1];
        }
#pragma unroll
        for (int j = 0; j < 4; ++j) {
            klB[j] = knots[(dl + j) * NBINS + iB[j]];
            krB[j] = knots[(dl + j) * NBINS + iB[j] + 1];
        }

        float zA[4], zB[4];
        float phpA = 1.0f, ssA = 0.0f, phpB = 1.0f, ssB = 0.0f;
        DIM_MATH(xqA.x, (dl + 0) * NBINS, iA[0], klA[0], krA[0], scale[0],
                 phpA, ssA, zA[0]);
        DIM_MATH(xqA.y, (dl + 1) * NBINS, iA[1], klA[1], krA[1], scale[1],
                 phpA, ssA, zA[1]);
        DIM_MATH(xqA.z, (dl + 2) * NBINS, iA[2], klA[2], krA[2], scale[2],
                 phpA, ssA, zA[2]);
        DIM_MATH(xqA.w, (dl + 3) * NBINS, iA[3], klA[3], krA[3], scale[3],
                 phpA, ssA, zA[3]);
        DIM_MATH(xqB.x, (dl + 0) * NBINS, iB[0], klB[0], krB[0], scale[0],
                 phpB, ssB, zB[0]);
        DIM_MATH(xqB.y, (dl + 1) * NBINS, iB[1], klB[1], krB[1], scale[1],
                 phpB, ssB, zB[1]);
        DIM_MATH(xqB.z, (dl + 2) * NBINS, iB[2], klB[2], krB[2], scale[2],
                 phpB, ssB, zB[2]);
        DIM_MATH(xqB.w, (dl + 3) * NBINS, iB[3], klB[3], krB[3], scale[3],
                 phpB, ssB, zB[3]);

        ((float4*)out)[(size_t)rA * (NDIM / 4) + qidx] =
            make_float4(zA[0], zA[1], zA[2], zA[3]);
        if (rB < B)
            ((float4*)out)[(size_t)rB * (NDIM / 4) + qidx] =
                make_float4(zB[0], zB[1], zB[2], zB[3]);

        // term = sum_j [log(p_hat_j) + 0.5 z^2 + log(sqrt(2pi))], p_hat=slope2/2:
        // const = 4*(ln(sqrt(2pi)) - ln2) = 4*0.22579135264472744
        float termA = fmaf(0.5f, ssA, 4.0f * 0.22579135264472744f) +
                      0.6931471805599453f * __builtin_amdgcn_logf(phpA);
        float termB = fmaf(0.5f, ssB, 4.0f * 0.22579135264472744f) +
                      0.6931471805599453f * __builtin_amdgcn_logf(phpB);

        termA += pair_swap_dpp(termA);     // partner lane covers the other 4 dims
        termB += pair_swap_dpp(termB);
        if ((threadIdx.x & 1) == 0) {
            if constexpr (USE_WS) {
                ws[(size_t)blockIdx.y * B + rA] = termA;   // coalesced partials
                if (rB < B) ws[(size_t)blockIdx.y * B + rB] = termB;
            } else {
                atomicAdd(out + (size_t)B * NDIM + rA, termA);
                if (rB < B) atomicAdd(out + (size_t)B * NDIM + rB, termB);
            }
        }

        xqA = xnA;
        xqB = xnB;
    }
}

extern "C" void kernel_launch(void* const* d_in, const int* in_sizes, int n_in,
                              void* d_out, int out_size, void* d_ws, size_t ws_size,
                              hipStream_t stream) {
    const float* x = (const float*)d_in[0];
    const float* xvals = (const float*)d_in[1];
    const float* cdf = (const float*)d_in[2];
    float* out = (float*)d_out;
    int B = in_sizes[0] / NDIM;

    const size_t ws_need = (size_t)DIM_GROUPS * B * sizeof(float);
    dim3 grid(ROW_BLOCKS, DIM_GROUPS);

    if (ws_size >= ws_need) {
        float* ws = (float*)d_ws;
        hipLaunchKernelGGL((mg_main<true>), grid, dim3(BLOCK_THREADS), 0, stream,
                           x, xvals, cdf, out, ws, B);
        hipLaunchKernelGGL(mg_reduce, dim3((B + 255) / 256), dim3(256), 0, stream,
                           ws, out + (size_t)B * NDIM, B);
    } else {
        hipLaunchKernelGGL(mg_zero, dim3((B + 1023) / 1024), dim3(1024), 0, stream,
                           out + (size_t)B * NDIM, B);
        hipLaunchKernelGGL((mg_main<false>), grid, dim3(BLOCK_THREADS), 0, stream,
                           x, xvals, cdf, out, (float*)nullptr, B);
    }
}

// Round 8
// 138.228 us; speedup vs baseline: 1.4737x; 1.4737x over previous
//
#include <hip/hip_runtime.h>
#include <math.h>

#define NBINS 1000
#define NDIM 64
#define DIMS_PER_BLOCK 8
#define DIM_GROUPS (NDIM / DIMS_PER_BLOCK)      // 8
#define BLOCK_THREADS 1024
#define ROWS_PER_ITER (BLOCK_THREADS / 2)       // 512 rows per block-iteration
#define ROW_BLOCKS 64                            // 512 blocks = 2/CU, ALL resident
                                                 // (single generation, no turnover).
                                                 // 64%8==0 -> all dim-groups of a row
                                                 // chunk on one XCD; partial-line
                                                 // merge OK (FETCH 38MB measured).
                                                 // STRUCTURE IS LOAD-BEARING, 3x
                                                 // confirmed: don't interleave distant
                                                 // rows (R3), don't shrink per-row
                                                 // footprint <32B (R5), don't widen
                                                 // the live row window (R7). Exactly
                                                 // 512 consecutive rows per body.

// zero the log_det region (atomic fallback path only)
__global__ __launch_bounds__(1024) void mg_zero(float* __restrict__ p, int n) {
    int i = blockIdx.x * blockDim.x + threadIdx.x;
    if (i < n) p[i] = 0.0f;
}

// final reduce: log_det[row] = sum over 8 dim-group partials in ws
__global__ __launch_bounds__(256) void mg_reduce(const float* __restrict__ ws,
                                                 float* __restrict__ out, int B) {
    int row = blockIdx.x * blockDim.x + threadIdx.x;
    if (row >= B) return;
    float s = 0.0f;
#pragma unroll
    for (int g = 0; g < DIM_GROUPS; ++g) s += ws[(size_t)g * B + row];
    out[row] = s;
}

// per-dim math in e-space (tables store c' = 2c-1, proven correct in R7 run):
// e = c'_l + slope2*(x-x_l) directly (no fmaf(2,u,-1)); slope2 = 2*p_hat; the
// /2 folds into the log-det constant. e-clamp +-0.99999 subsumes the ref's
// u-clip to (1e-6,1-1e-6) exactly. Fix-up walk compares STORED x knots -> bin
// selection stays exact. MACRO so knots[] stays a direct LDS access.
#define DIM_MATH(xd_, base_, i_, a_, b_, sc_, php_, ss_, zout_)                   \
    {                                                                             \
        float xd = (xd_);                                                         \
        int i = (i_);                                                             \
        float2 a = (a_), b = (b_);                                                \
        if (__builtin_expect((xd > b.x && i < NBINS - 2) ||                       \
                             (xd <= a.x && i > 0), 0)) {                          \
            while (xd > b.x && i < NBINS - 2) {                                   \
                ++i; a = b; b = knots[(base_) + i + 1];                           \
            }                                                                     \
            while (xd <= a.x && i > 0) {                                          \
                --i; b = a; a = knots[(base_) + i];                               \
            }                                                                     \
        }                                                                         \
        float slope2 = (b.y - a.y) * (sc_);     /* = 2*p_hat (const inv-step) */  \
        float e = fmaf(slope2, xd - a.x, a.y);                                    \
        float ph2 = fmaxf(slope2, 2e-12f);                                        \
        float e1 = fminf(fmaxf(e, -0.99999f), 0.99999f);                          \
        float wv = -0.6931471805599453f *                                         \
                   __builtin_amdgcn_logf(fmaf(-e1, e1, 1.0f));                    \
        float t = wv - 2.5f;                                                      \
        float p = 2.81022636e-08f;                                                \
        p = fmaf(p, t, 3.43273939e-07f);                                          \
        p = fmaf(p, t, -3.5233877e-06f);                                          \
        p = fmaf(p, t, -4.39150654e-06f);                                         \
        p = fmaf(p, t, 0.00021858087f);                                           \
        p = fmaf(p, t, -0.00125372503f);                                          \
        p = fmaf(p, t, -0.00417768164f);                                          \
        p = fmaf(p, t, 0.246640727f);                                             \
        p = fmaf(p, t, 1.50140941f);                                              \
        if (wv >= 5.0f) {                                                         \
            float tq = sqrtf(wv) - 3.0f;                                          \
            float pt = -0.000200214257f;                                          \
            pt = fmaf(pt, tq, 0.000100950558f);                                   \
            pt = fmaf(pt, tq, 0.00134934322f);                                    \
            pt = fmaf(pt, tq, -0.00367342844f);                                   \
            pt = fmaf(pt, tq, 0.00573950773f);                                    \
            pt = fmaf(pt, tq, -0.0076224613f);                                    \
            pt = fmaf(pt, tq, 0.00943887047f);                                    \
            pt = fmaf(pt, tq, 1.00167406f);                                       \
            pt = fmaf(pt, tq, 2.83297682f);                                       \
            p = pt;                                                               \
        }                                                                         \
        float z = 1.4142135623730951f * p * e1; /* |z|<=4.418, ref clamp dead */  \
        (zout_) = z;                                                              \
        (ss_) = fmaf(z, z, (ss_));                                                \
        (php_) *= ph2;                                                            \
    }

// float-domain clamp-to-[0,998] via single v_med3_f32, then convert.
__device__ __forceinline__ int bin_guess(float xv, float sc, float bi) {
    return (int)__builtin_amdgcn_fmed3f(fmaf(xv, sc, bi), 0.0f,
                                        (float)(NBINS - 2));
}

// lane0<->lane1 pair swap as pure VALU (DPP quad_perm [1,0,3,2] = 0xB1).
// No lgkm event -> the reduce never drains outstanding LDS gathers (R6 win).
__device__ __forceinline__ float pair_swap_dpp(float v) {
    return __int_as_float(__builtin_amdgcn_update_dpp(
        __float_as_int(v), __float_as_int(v), 0xB1, 0xF, 0xF, true));
}

// Block owns 8 dims; knots (x_i, 2c_i-1) staged in LDS (64 KB).
// MEMORY STRUCTURE = R6 verbatim (measured best: 47.3us, FETCH 38MB).
// Pipeline per body k: issue x(k+2) -> math(k) [gathers issued in body k-1,
// full body of lgkm slack] -> bins+gathers(k+1) from x(k+1) [arrived: issued
// 2 bodies ago, no vm wait] -> stores + DPP reduce [no lgkm wait].
template <bool USE_WS>
__global__ __launch_bounds__(BLOCK_THREADS, 8)
void mg_main(const float* __restrict__ x,
             const float* __restrict__ xvals,
             const float* __restrict__ cdf,
             float* __restrict__ out, float* __restrict__ ws, int B) {
    __shared__ float2 knots[DIMS_PER_BLOCK * NBINS];   // 64000 B

    const int dimbase = blockIdx.y * DIMS_PER_BLOCK;

    {   // vectorized stage: 2000 float4s from each table; c -> 2c-1 (e-space)
        const float4* xv4 = (const float4*)(xvals + (size_t)dimbase * NBINS);
        const float4* cd4 = (const float4*)(cdf + (size_t)dimbase * NBINS);
        for (int k = threadIdx.x; k < DIMS_PER_BLOCK * NBINS / 4; k += BLOCK_THREADS) {
            float4 a = xv4[k], c = cd4[k];
            knots[k * 4 + 0] = make_float2(a.x, fmaf(2.0f, c.x, -1.0f));
            knots[k * 4 + 1] = make_float2(a.y, fmaf(2.0f, c.y, -1.0f));
            knots[k * 4 + 2] = make_float2(a.z, fmaf(2.0f, c.z, -1.0f));
            knots[k * 4 + 3] = make_float2(a.w, fmaf(2.0f, c.w, -1.0f));
        }
    }
    __syncthreads();

    const int dl = (threadIdx.x & 1) * 4;                // local dims dl..dl+3
    const int qidx = blockIdx.y * 2 + (threadIdx.x & 1); // float4 index within row

    float scale[4], bias[4];
#pragma unroll
    for (int j = 0; j < 4; ++j) {
        float l = knots[(dl + j) * NBINS].x;
        float h = knots[(dl + j) * NBINS + NBINS - 1].x;
        float s = (float)(NBINS - 1) / (h - l);          // == 1/step_d
        scale[j] = s;
        bias[j] = -l * s;
    }

    const int rstride = gridDim.x * ROWS_PER_ITER;
    int row = blockIdx.x * ROWS_PER_ITER + (threadIdx.x >> 1);

    // prologue: x for iter 0 and 1; bins+gathers for iter 0
    float4 xq = make_float4(0.f, 0.f, 0.f, 0.f);
    float4 xn = make_float4(0.f, 0.f, 0.f, 0.f);
    if (row < B) xq = ((const float4*)x)[(size_t)row * (NDIM / 4) + qidx];
    if (row + rstride < B)
        xn = ((const float4*)x)[(size_t)(row + rstride) * (NDIM / 4) + qidx];

    int ii[4];
    float2 kl[4], kr[4];
    {
        float xv[4] = {xq.x, xq.y, xq.z, xq.w};
#pragma unroll
        for (int j = 0; j < 4; ++j) ii[j] = bin_guess(xv[j], scale[j], bias[j]);
#pragma unroll
        for (int j = 0; j < 4; ++j) {
            kl[j] = knots[(dl + j) * NBINS + ii[j]];
            kr[j] = knots[(dl + j) * NBINS + ii[j] + 1];
        }
    }

    for (; row < B; row += rstride) {
        // issue x(k+2): consumed by bins+gathers two bodies from now
        const int prow = row + 2 * rstride;
        float4 xn2 = make_float4(0.f, 0.f, 0.f, 0.f);
        if (prow < B) xn2 = ((const float4*)x)[(size_t)prow * (NDIM / 4) + qidx];

        // math on current row: gathers issued LAST body, full body of slack
        float z4[4], php = 1.0f, sumsq = 0.0f;
        DIM_MATH(xq.x, (dl + 0) * NBINS, ii[0], kl[0], kr[0], scale[0],
                 php, sumsq, z4[0]);
        DIM_MATH(xq.y, (dl + 1) * NBINS, ii[1], kl[1], kr[1], scale[1],
                 php, sumsq, z4[1]);
        DIM_MATH(xq.z, (dl + 2) * NBINS, ii[2], kl[2], kr[2], scale[2],
                 php, sumsq, z4[2]);
        DIM_MATH(xq.w, (dl + 3) * NBINS, ii[3], kl[3], kr[3], scale[3],
                 php, sumsq, z4[3]);

        // bins + gathers for NEXT body from xn (loaded 2 bodies ago, no vm wait)
        {
            float xv[4] = {xn.x, xn.y, xn.z, xn.w};
#pragma unroll
            for (int j = 0; j < 4; ++j)
                ii[j] = bin_guess(xv[j], scale[j], bias[j]);  // safe for dummy 0
#pragma unroll
            for (int j = 0; j < 4; ++j) {
                kl[j] = knots[(dl + j) * NBINS + ii[j]];
                kr[j] = knots[(dl + j) * NBINS + ii[j] + 1];
            }
        }

        ((float4*)out)[(size_t)row * (NDIM / 4) + qidx] =
            make_float4(z4[0], z4[1], z4[2], z4[3]);

        // term = sum_j [log(p_hat_j) + 0.5 z^2 + log(sqrt(2pi))], p_hat=slope2/2:
        // const = 4*(ln(sqrt(2pi)) - ln2) = 4*0.22579135264472744
        float term = fmaf(0.5f, sumsq, 4.0f * 0.22579135264472744f) +
                     0.6931471805599453f * __builtin_amdgcn_logf(php);

        term += pair_swap_dpp(term);       // partner lane covers the other 4 dims
        if ((threadIdx.x & 1) == 0) {
            if constexpr (USE_WS)
                ws[(size_t)blockIdx.y * B + row] = term;   // coalesced partial
            else
                atomicAdd(out + (size_t)B * NDIM + row, term);
        }

        xq = xn;
        xn = xn2;
    }
}

extern "C" void kernel_launch(void* const* d_in, const int* in_sizes, int n_in,
                              void* d_out, int out_size, void* d_ws, size_t ws_size,
                              hipStream_t stream) {
    const float* x = (const float*)d_in[0];
    const float* xvals = (const float*)d_in[1];
    const float* cdf = (const float*)d_in[2];
    float* out = (float*)d_out;
    int B = in_sizes[0] / NDIM;

    const size_t ws_need = (size_t)DIM_GROUPS * B * sizeof(float);
    dim3 grid(ROW_BLOCKS, DIM_GROUPS);

    if (ws_size >= ws_need) {
        float* ws = (float*)d_ws;
        hipLaunchKernelGGL((mg_main<true>), grid, dim3(BLOCK_THREADS), 0, stream,
                           x, xvals, cdf, out, ws, B);
        hipLaunchKernelGGL(mg_reduce, dim3((B + 255) / 256), dim3(256), 0, stream,
                           ws, out + (size_t)B * NDIM, B);
    } else {
        hipLaunchKernelGGL(mg_zero, dim3((B + 1023) / 1024), dim3(1024), 0, stream,
                           out + (size_t)B * NDIM, B);
        hipLaunchKernelGGL((mg_main<false>), grid, dim3(BLOCK_THREADS), 0, stream,
                           x, xvals, cdf, out, (float*)nullptr, B);
    }
}